// Round 4
// baseline (38.213 us; speedup 1.0000x reference)
//
#include <hip/hip_runtime.h>

#define EMB 200
#define U_DIM 32
#define T_DIM 4
#define DIM_A 32
#define NN 10
#define BLK 1024
#define NWAVE 16
#define BPW 4
#define TW_FLOATS (T_DIM * U_DIM * EMB)   // 25600 floats = 102400 B

__global__ __launch_bounds__(BLK, 4) void gatne_fused(
    const int* __restrict__ train_inputs,
    const int* __restrict__ train_types,
    const int* __restrict__ node_neigh,
    const float* __restrict__ node_emb,
    const float* __restrict__ node_type_emb,
    const float* __restrict__ tw,
    const float* __restrict__ tw1,
    const float* __restrict__ tw2,
    float* __restrict__ out)
{
    __shared__ float s_tw[TW_FLOATS];                 // 102.4 KB: all 4 type slices
    __shared__ float s_nte[NWAVE][T_DIM][U_DIM];      // 8 KB
    __shared__ float s_comb[NWAVE][U_DIM];            // 2 KB

    const int wid  = threadIdx.x >> 6;
    const int lane = threadIdx.x & 63;
    const int u    = lane & 31;
    const int th   = lane >> 5;
    const int base = blockIdx.x * (NWAVE * BPW);

    // prologue: issue b0's neighbor-index load before staging
    int nb[2];
    nb[0] = (lane < T_DIM * NN) ? node_neigh[(base + wid) * T_DIM * NN + lane] : 0;
    nb[1] = 0;

    // ---- stage all of tw into LDS (one-time, ~102 KB) ----
    {
        const float4* src = (const float4*)tw;
        float4*       dst = (float4*)s_tw;
        #pragma unroll
        for (int k = 0; k < 7; ++k) {
            const int i = threadIdx.x + k * BLK;
            if (i < TW_FLOATS / 4) dst[i] = src[i];
        }
    }
    __syncthreads();

    // gather staging registers: g[buf][tt][n], double-buffered across b's
    float g[2][2][NN];

    // issue gathers for b0
    #pragma unroll
    for (int tt = 0; tt < 2; ++tt) {
        const int t = tt * 2 + th;
        #pragma unroll
        for (int n = 0; n < NN; ++n) {
            const int idx = __shfl(nb[0], t * NN + n, 64);
            g[0][tt][n] = node_type_emb[((long)idx * T_DIM + t) * U_DIM + u];
        }
    }

    #pragma unroll
    for (int i = 0; i < BPW; ++i) {
        const int cb   = i & 1;
        const int nbuf = cb ^ 1;
        const int b    = base + i * NWAVE + wid;

        // issue next b's neighbor indices (addresses for next gather burst)
        if (i + 1 < BPW)
            nb[nbuf] = (lane < T_DIM * NN)
                     ? node_neigh[(base + (i + 1) * NWAVE + wid) * T_DIM * NN + lane] : 0;

        const int type = train_types[b];     // wave-uniform
        const int node = train_inputs[b];    // wave-uniform

        // issue this b's node-embedding row load early (consumed after attention)
        float4 nv = make_float4(0.f, 0.f, 0.f, 0.f);
        if (lane < EMB / 4)
            nv = *(const float4*)(node_emb + (size_t)node * EMB + lane * 4);

        // reduce staged gathers -> s_nte (frees g[cb])
        #pragma unroll
        for (int tt = 0; tt < 2; ++tt) {
            const int t = tt * 2 + th;
            float a0 = 0.f;
            #pragma unroll
            for (int n = 0; n < NN; ++n) a0 += g[cb][tt][n];
            s_nte[wid][t][u] = a0;
        }

        // issue gathers for NEXT b now — they fly under attention + matvec (T14)
        if (i + 1 < BPW) {
            #pragma unroll
            for (int tt = 0; tt < 2; ++tt) {
                const int t = tt * 2 + th;
                #pragma unroll
                for (int n = 0; n < NN; ++n) {
                    const int idx = __shfl(nb[nbuf], t * NN + n, 64);
                    g[nbuf][tt][n] = node_type_emb[((long)idx * T_DIM + t) * U_DIM + u];
                }
            }
        }

        // attention
        const float* tw1p = tw1 + type * U_DIM * DIM_A;
        const float  w2   = tw2[type * DIM_A + u];
        float sc[2];
        #pragma unroll
        for (int tt = 0; tt < 2; ++tt) {
            const int t = tt * 2 + th;
            float a1 = 0.f;
            #pragma unroll
            for (int uu = 0; uu < U_DIM; ++uu)
                a1 += s_nte[wid][t][uu] * tw1p[uu * DIM_A + u];
            float s = tanhf(a1) * w2;
            #pragma unroll
            for (int m = 1; m < 32; m <<= 1) s += __shfl_xor(s, m, 64);
            sc[tt] = s;
        }
        const float o0 = __shfl_xor(sc[0], 32, 64);
        const float o1 = __shfl_xor(sc[1], 32, 64);
        const float s0 = th ? o0    : sc[0];
        const float s1 = th ? sc[0] : o0;
        const float s2 = th ? o1    : sc[1];
        const float s3 = th ? sc[1] : o1;

        const float mx  = fmaxf(fmaxf(s0, s1), fmaxf(s2, s3));
        const float e0  = __expf(s0 - mx), e1 = __expf(s1 - mx);
        const float e2  = __expf(s2 - mx), e3 = __expf(s3 - mx);
        const float inv = 1.f / (e0 + e1 + e2 + e3);
        const float comb = (e0 * s_nte[wid][0][u] + e1 * s_nte[wid][1][u] +
                            e2 * s_nte[wid][2][u] + e3 * s_nte[wid][3][u]) * inv;
        if (lane < 32) s_comb[wid][u] = comb;

        // matvec from LDS-resident tw
        const float* twp = s_tw + type * U_DIM * EMB;
        float4 v = nv;
        if (lane < EMB / 4) {
            #pragma unroll 8
            for (int uu = 0; uu < U_DIM; ++uu) {
                const float  cg = s_comb[wid][uu];
                const float4 w  = *(const float4*)(twp + uu * EMB + lane * 4);
                v.x += cg * w.x; v.y += cg * w.y; v.z += cg * w.z; v.w += cg * w.w;
            }
        }
        float ss = (lane < EMB / 4) ? (v.x * v.x + v.y * v.y + v.z * v.z + v.w * v.w) : 0.f;
        #pragma unroll
        for (int m = 1; m < 64; m <<= 1) ss += __shfl_xor(ss, m, 64);
        const float rinv = 1.f / fmaxf(sqrtf(ss), 1e-12f);
        if (lane < EMB / 4) {
            float4 o = make_float4(v.x * rinv, v.y * rinv, v.z * rinv, v.w * rinv);
            *(float4*)(out + (size_t)b * EMB + lane * 4) = o;
        }
    }
}

extern "C" void kernel_launch(void* const* d_in, const int* in_sizes, int n_in,
                              void* d_out, int out_size, void* d_ws, size_t ws_size,
                              hipStream_t stream) {
    const int*   train_inputs = (const int*)d_in[0];
    const int*   train_types  = (const int*)d_in[1];
    const int*   node_neigh   = (const int*)d_in[2];
    const float* node_emb     = (const float*)d_in[3];
    const float* node_type_e  = (const float*)d_in[4];
    const float* tw           = (const float*)d_in[5];
    const float* tw1          = (const float*)d_in[6];
    const float* tw2          = (const float*)d_in[7];
    float*       out          = (float*)d_out;

    const int B = in_sizes[0];                 // 16384
    const int blocks = B / (NWAVE * BPW);      // 256 — one block per CU

    gatne_fused<<<blocks, BLK, 0, stream>>>(
        train_inputs, train_types, node_neigh,
        node_emb, node_type_e, tw, tw1, tw2, out);
}